// Round 4
// baseline (60.253 us; speedup 1.0000x reference)
//
#include <hip/hip_runtime.h>
#include <hip/hip_bf16.h>
#include <stdint.h>

// EnergyAttention: out = -sum(logsumexp(SCALE * (Q K^T), axis=-1)) / SCALE
// Q = hs @ qp^T + qb (pre-scaled by SCALE*log2e), K = hs @ kp^T + kb, bf16.

typedef __bf16 bf16_t;
typedef bf16_t bf16x8 __attribute__((ext_vector_type(8)));
typedef float f32x4 __attribute__((ext_vector_type(4)));
typedef float f32x16 __attribute__((ext_vector_type(16)));

#define MFMA16(a,b,c) __builtin_amdgcn_mfma_f32_16x16x32_bf16(a,b,c,0,0,0)
#define MFMA32(a,b,c) __builtin_amdgcn_mfma_f32_32x32x16_bf16(a,b,c,0,0,0)
#define GLL16(g, l) __builtin_amdgcn_global_load_lds(                       \
    (const __attribute__((address_space(1))) void*)(g),                     \
    (__attribute__((address_space(3))) void*)(l), 16, 0, 0)

#define SB0     __builtin_amdgcn_sched_barrier(0)
#define BARRIER __builtin_amdgcn_s_barrier()
#define VMCNT4  do { SB0; asm volatile("s_waitcnt vmcnt(4)" ::: "memory"); SB0; } while(0)
#define LGKM0   do { asm volatile("s_waitcnt lgkmcnt(0)" ::: "memory"); SB0; } while(0)

static constexpr int SEQ = 2048, BATCH = 2, EMBED = 1024, NH = 16, QKD = 64;
static constexpr int M_TOT = BATCH * SEQ;   // 4096
static constexpr int N_TOT = 2 * NH * QKD;  // 2048 (Q cols 0..1023, K cols 1024..2047)
static constexpr float C1 = 0.125f * 1.44269504088896340736f; // SCALE*log2(e)

// ---- single-launch f32 -> bf16 convert of hs, qp, kp ----
__global__ __launch_bounds__(256) void cvt_kernel(
    const float* __restrict__ hs, const float* __restrict__ qp,
    const float* __restrict__ kp, bf16_t* __restrict__ hsb,
    bf16_t* __restrict__ projb)
{
    int i = blockIdx.x * 256 + threadIdx.x;   // vec8 index, 786432 total
    const float* src; bf16_t* dst;
    if (i < 524288) { src = hs + (size_t)i * 8; dst = hsb + (size_t)i * 8; }
    else {
        int j = i - 524288;
        dst = projb + (size_t)j * 8;
        src = (j < 131072) ? qp + (size_t)j * 8 : kp + (size_t)(j - 131072) * 8;
    }
    f32x4 a = ((const f32x4*)src)[0], b = ((const f32x4*)src)[1];
    bf16x8 r;
    r[0]=(bf16_t)a[0]; r[1]=(bf16_t)a[1]; r[2]=(bf16_t)a[2]; r[3]=(bf16_t)a[3];
    r[4]=(bf16_t)b[0]; r[5]=(bf16_t)b[1]; r[6]=(bf16_t)b[2]; r[7]=(bf16_t)b[3];
    *(bf16x8*)dst = r;
}

// ---- Phase 1: C[m][n] = sum_d A[m][d]*B[n][d] + bias, bf16 out ----
// 128x128 tile, BK=64, double-buffered LDS, 4-phase counted-vmcnt schedule
// (T3+T4+T5). Halves = 64-row slabs of A / B; wave frags interleaved
// (row = mt*32 + wr*16) so each phase needs only previously-landed halves.
// LDS rows 128B, granule XOR-swizzle by row&7 (pre-swizzled global source).
__global__ __launch_bounds__(256, 2) void proj_kernel(
    const bf16_t* __restrict__ A, const bf16_t* __restrict__ B,
    const float* __restrict__ qb, const float* __restrict__ kb,
    bf16_t* __restrict__ C)
{
    __shared__ __align__(16) char sA[2][16384];
    __shared__ __align__(16) char sB[2][16384];
    const int t = threadIdx.x, lane = t & 63, wv = t >> 6;
    const int bid = blockIdx.x;
    const int xcd = bid & 7, idx = bid >> 3;
    const int am0 = (xcd * 4 + (idx >> 4)) * 128;   // M-strip per XCD
    const int bn0 = (idx & 15) * 128;
    const int wr = wv >> 1, wc = wv & 1;
    const int l15 = lane & 15, g = lane >> 4;

    // staging: half h, load l covers LDS rows h*64 + l*32 + wv*8 + (lane>>3),
    // granule lane&7; global source granule pre-swizzled by row&7 = (lane>>3)&7.
    const int sgr = (lane & 7) ^ ((lane >> 3) & 7);
    const bf16_t* gA[2][2];
    const bf16_t* gB[2][2];
#pragma unroll
    for (int h = 0; h < 2; ++h)
#pragma unroll
        for (int l = 0; l < 2; ++l) {
            int row = h * 64 + l * 32 + wv * 8 + (lane >> 3);
            gA[h][l] = A + (size_t)(am0 + row) * EMBED + 8 * sgr;
            gB[h][l] = B + (size_t)(bn0 + row) * EMBED + 8 * sgr;
        }

#define STAGE_A(BUF,H,KK) do {                                              \
    GLL16(gA[H][0] + (KK), &sA[BUF][(H)*8192 +        wv*1024]);            \
    GLL16(gA[H][1] + (KK), &sA[BUF][(H)*8192 + 4096 + wv*1024]); } while(0)
#define STAGE_B(BUF,H,KK) do {                                              \
    GLL16(gB[H][0] + (KK), &sB[BUF][(H)*8192 +        wv*1024]);            \
    GLL16(gB[H][1] + (KK), &sB[BUF][(H)*8192 + 4096 + wv*1024]); } while(0)
// frag read: row = mt*32 + (wr|wc)*16 + l15, source granule (s<<2)|g, stored at ^ (row&7)
#define READ_A(BUF,MT,S,DST) do { int row_ = (MT)*32 + wr*16 + l15;         \
    DST = *(const bf16x8*)&sA[BUF][row_*128 + 16*((((S)<<2)|g) ^ (row_&7))]; } while(0)
#define READ_B(BUF,NT,S,DST) do { int row_ = (NT)*32 + wc*16 + l15;         \
    DST = *(const bf16x8*)&sB[BUF][row_*128 + 16*((((S)<<2)|g) ^ (row_&7))]; } while(0)
#define MFMA_Q(MT0,NT0) do {                                                \
    __builtin_amdgcn_s_setprio(1);                                          \
    _Pragma("unroll") for (int s_ = 0; s_ < 2; ++s_)                        \
    _Pragma("unroll") for (int m_ = 0; m_ < 2; ++m_)                        \
    _Pragma("unroll") for (int n_ = 0; n_ < 2; ++n_)                        \
        acc[(MT0)+m_][(NT0)+n_] =                                           \
            MFMA16(aF[(MT0)+m_][s_], bF[(NT0)+n_][s_], acc[(MT0)+m_][(NT0)+n_]); \
    __builtin_amdgcn_s_setprio(0); SB0; } while(0)

    bf16x8 aF[4][2], bF[4][2];
    f32x4 acc[4][4] = {};

    // prologue: stage tile 0 (order Ah0, Bh0, Ah1, Bh1 - matches steady state)
    STAGE_A(0, 0, 0); STAGE_B(0, 0, 0); STAGE_A(0, 1, 0); STAGE_B(0, 1, 0);

#define TILE(BUF, TT) do {                                                  \
    const int nk_ = ((TT) < 15 ? (TT) + 1 : 15) * 64;                       \
    /* P1: needs A-h0 + B-h0 of tile TT (oldest 4 of 8 in flight) */        \
    VMCNT4; BARRIER; SB0;                                                   \
    STAGE_A(BUF^1, 0, nk_);                                                 \
    READ_A(BUF,0,0,aF[0][0]); READ_A(BUF,0,1,aF[0][1]);                     \
    READ_A(BUF,1,0,aF[1][0]); READ_A(BUF,1,1,aF[1][1]);                     \
    READ_B(BUF,0,0,bF[0][0]); READ_B(BUF,0,1,bF[0][1]);                     \
    READ_B(BUF,1,0,bF[1][0]); READ_B(BUF,1,1,bF[1][1]);                     \
    LGKM0; MFMA_Q(0, 0);                                                    \
    /* P2: needs A-h1 */                                                    \
    VMCNT4; BARRIER; SB0;                                                   \
    STAGE_B(BUF^1, 0, nk_);                                                 \
    READ_A(BUF,2,0,aF[2][0]); READ_A(BUF,2,1,aF[2][1]);                     \
    READ_A(BUF,3,0,aF[3][0]); READ_A(BUF,3,1,aF[3][1]);                     \
    LGKM0; MFMA_Q(2, 0);                                                    \
    /* P3: needs B-h1 (all of tile TT landed) */                            \
    VMCNT4; BARRIER; SB0;                                                   \
    STAGE_A(BUF^1, 1, nk_);                                                 \
    READ_B(BUF,2,0,bF[2][0]); READ_B(BUF,2,1,bF[2][1]);                     \
    READ_B(BUF,3,0,bF[3][0]); READ_B(BUF,3,1,bF[3][1]);                     \
    LGKM0; MFMA_Q(2, 2);                                                    \
    /* P4: pure MFMA from held regs, no wait/barrier */                     \
    STAGE_B(BUF^1, 1, nk_);                                                 \
    MFMA_Q(0, 2); } while(0)

    for (int tp = 0; tp < 8; ++tp) {
        TILE(0, tp * 2);
        TILE(1, tp * 2 + 1);
    }

    // epilogue: C/D 16x16 layout col=lane&15, row=(lane>>4)*4+j
#pragma unroll
    for (int nt = 0; nt < 4; ++nt) {
        int col = bn0 + nt * 32 + wc * 16 + l15;
        float bias, scale;
        if (col < NH * QKD) { bias = qb[col & 63]; scale = C1; }   // Q: fold SCALE*log2e
        else                { bias = kb[col & 63]; scale = 1.0f; }
#pragma unroll
        for (int mt = 0; mt < 4; ++mt)
#pragma unroll
            for (int j = 0; j < 4; ++j) {
                int row = am0 + mt * 32 + wr * 16 + g * 4 + j;
                C[(size_t)row * N_TOT + col] = (bf16_t)((acc[mt][nt][j] + bias) * scale);
            }
    }
#undef TILE
#undef MFMA_Q
#undef READ_A
#undef READ_B
#undef STAGE_A
#undef STAGE_B
}

// ---- Phase 2: per (b,h): rowwise sum of exp2(Q K^T), partial sum of log2 ----
// Operand-swapped MFMA: s = mfma(K, Q) puts the K-row (reduction) axis on
// registers -> in-register exp2 accumulation. No LDS staging (K L2-resident),
// no barriers in the main loop. T5 setprio around the MFMA cluster.
__global__ __launch_bounds__(256) void lse_kernel(
    const bf16_t* __restrict__ qk, float* __restrict__ partials)
{
    __shared__ float rows_s[4][128];
    __shared__ float ws[4];
    const int t = threadIdx.x, lane = t & 63, wv = t >> 6;
    const int bid = blockIdx.x;
    const int xcd = bid & 7, idx = bid >> 3;
    const int pair = xcd * 4 + (idx >> 4);    // all 16 tiles of a pair on one XCD
    const int tile = idx & 15;
    const int b = pair >> 4, h = pair & 15;
    const int qr0 = tile * 128;
    const int l31 = lane & 31, g5 = lane >> 5;
    const size_t base = (size_t)b * SEQ;

    // Q fragments (B-operand): lane holds Q-row qr0+mt*32+l31, k = kf*16+g5*8
    bf16x8 qf[4][4];
#pragma unroll
    for (int mt = 0; mt < 4; ++mt) {
        const bf16_t* qp_ = qk + (base + qr0 + mt * 32 + l31) * N_TOT + h * QKD + g5 * 8;
#pragma unroll
        for (int kf = 0; kf < 4; ++kf)
            qf[mt][kf] = *(const bf16x8*)(qp_ + kf * 16);
    }

    // K fragment base (A-operand): lane holds K-row (wv*512 + ct*32 + l31)
    const bf16_t* kb_ = qk + (base + wv * 512 + l31) * N_TOT + NH * QKD + h * QKD + g5 * 8;

    float sume[4] = {0.f, 0.f, 0.f, 0.f};

    bf16x8 kv[4];
#pragma unroll
    for (int kf = 0; kf < 4; ++kf) kv[kf] = *(const bf16x8*)(kb_ + kf * 16);

    for (int ct = 0; ct < 16; ++ct) {
        // prefetch next K-frag set (clamped on last iter)
        bf16x8 kn[4];
        const bf16_t* kn_p = kb_ + (size_t)((ct < 15 ? ct + 1 : 15) * 32) * N_TOT;
#pragma unroll
        for (int kf = 0; kf < 4; ++kf) kn[kf] = *(const bf16x8*)(kn_p + kf * 16);

        // 16 back-to-back MFMA32 (4 independent accumulators), then 64 exp2
        f32x16 sacc[4];
        __builtin_amdgcn_s_setprio(1);
#pragma unroll
        for (int mt = 0; mt < 4; ++mt) {
            f32x16 z = {};
            sacc[mt] = z;
#pragma unroll
            for (int kf = 0; kf < 4; ++kf)
                sacc[mt] = MFMA32(kv[kf], qf[mt][kf], sacc[mt]);
        }
        __builtin_amdgcn_s_setprio(0);
#pragma unroll
        for (int mt = 0; mt < 4; ++mt) {
            float e = 0.f;
#pragma unroll
            for (int j = 0; j < 16; ++j)
                e += __builtin_amdgcn_exp2f(sacc[mt][j]);
            sume[mt] += e;
        }
#pragma unroll
        for (int kf = 0; kf < 4; ++kf) kv[kf] = kn[kf];
    }

    // lane + its g5-partner cover all 32 K-rows of each ct for the same Q-row
#pragma unroll
    for (int mt = 0; mt < 4; ++mt) {
        float v = sume[mt] + __shfl_xor(sume[mt], 32);
        if (g5 == 0) rows_s[wv][mt * 32 + l31] = v;
    }
    __syncthreads();

    float lg = 0.f;
    if (t < 128) {
        float tot = rows_s[0][t] + rows_s[1][t] + rows_s[2][t] + rows_s[3][t];
        lg = __builtin_amdgcn_logf(tot);   // v_log_f32 = log2
    }
#pragma unroll
    for (int m = 1; m < 64; m <<= 1) lg += __shfl_xor(lg, m);
    if (lane == 0) ws[wv] = lg;
    __syncthreads();
    if (t == 0)
        partials[bid] = ws[0] + ws[1] + ws[2] + ws[3];
}

__global__ __launch_bounds__(256) void final_kernel(
    const float* __restrict__ partials, int n, float* __restrict__ out)
{
    float s = 0.f;
    for (int i = threadIdx.x; i < n; i += 256) s += partials[i];
#pragma unroll
    for (int m = 1; m < 64; m <<= 1) s += __shfl_xor(s, m);
    __shared__ float wsf[4];
    const int wave = threadIdx.x >> 6, lane = threadIdx.x & 63;
    if (lane == 0) wsf[wave] = s;
    __syncthreads();
    if (threadIdx.x == 0)
        out[0] = -8.0f * 0.69314718055994530942f * (wsf[0] + wsf[1] + wsf[2] + wsf[3]);
}

extern "C" void kernel_launch(void* const* d_in, const int* in_sizes, int n_in,
                              void* d_out, int out_size, void* d_ws, size_t ws_size,
                              hipStream_t stream)
{
    const float* hs = (const float*)d_in[0];
    const float* qp = (const float*)d_in[1];
    const float* kp = (const float*)d_in[2];
    const float* qb = (const float*)d_in[3];
    const float* kb = (const float*)d_in[4];

    // ws layout: hsb (8MB) | projb (4MB) | qk (16MB) | partials (2KB)
    bf16_t* hsb   = (bf16_t*)d_ws;
    bf16_t* projb = hsb + (size_t)M_TOT * EMBED;
    bf16_t* qkb   = projb + (size_t)N_TOT * EMBED;
    float*  partials = (float*)(qkb + (size_t)M_TOT * N_TOT);
    float*  out = (float*)d_out;

    cvt_kernel<<<3072, 256, 0, stream>>>(hs, qp, kp, hsb, projb);
    proj_kernel<<<512, 256, 0, stream>>>(hsb, projb, qb, kb, qkb);
    lse_kernel<<<512, 256, 0, stream>>>(qkb, partials);
    final_kernel<<<1, 256, 0, stream>>>(partials, 512, out);
}